// Round 1
// baseline (86.160 us; speedup 1.0000x reference)
//
#include <hip/hip_runtime.h>

// Mutual information of an 8192x8192 fp32 contingency table.
// MI = sum_{C>0} C*log2(C) - sum_i mx_i*log2(mx_i) - sum_j my_j*log2(my_j)
// (exact algebraic rewrite of the reference: masked sums of C equal the full
//  marginals because zero entries contribute nothing).

#define NROWS 8192
#define MCOLS 8192

__inline__ __device__ float waveReduceSum(float v) {
    // full 64-lane butterfly
    #pragma unroll
    for (int off = 32; off > 0; off >>= 1)
        v += __shfl_xor(v, off, 64);
    return v;
}

// Main streaming pass: each block owns a 256x256 tile.
// Produces: mx[row] (atomic), my[col] (atomic), s1 = sum C*log2(C) (atomic).
__global__ __launch_bounds__(256) void mi_main(const float* __restrict__ C,
                                               float* __restrict__ mx,
                                               float* __restrict__ my,
                                               float* __restrict__ s1) {
    const int tcol = blockIdx.x * 256;   // tile column base
    const int trow = blockIdx.y * 256;   // tile row base
    const int tid  = threadIdx.x;
    const int lane = tid & 63;
    const int wave = tid >> 6;

    __shared__ float lds_col[4][256];
    __shared__ float lds_s1[4];

    // Per-thread column accumulators: this thread always touches columns
    // tcol + lane*4 + {0..3} (same for every row it visits).
    float c0 = 0.f, c1 = 0.f, c2 = 0.f, c3 = 0.f;
    float s1_local = 0.f;

    const int colbase = tcol + lane * 4;
    const float* base = C + (size_t)trow * MCOLS + colbase;

    #pragma unroll 4
    for (int i = 0; i < 64; ++i) {
        const int rlocal = i * 4 + wave;           // row within tile, one row per wave
        const float4 v = *reinterpret_cast<const float4*>(base + (size_t)rlocal * MCOLS);

        // masked C*log2(C)
        float t0 = (v.x > 0.f) ? v.x * __log2f(v.x) : 0.f;
        float t1 = (v.y > 0.f) ? v.y * __log2f(v.y) : 0.f;
        float t2 = (v.z > 0.f) ? v.z * __log2f(v.z) : 0.f;
        float t3 = (v.w > 0.f) ? v.w * __log2f(v.w) : 0.f;
        s1_local += (t0 + t1) + (t2 + t3);

        // column partials (register-resident)
        c0 += v.x; c1 += v.y; c2 += v.z; c3 += v.w;

        // row partial: whole row segment lives in this one wave
        float p = (v.x + v.y) + (v.z + v.w);
        p = waveReduceSum(p);
        if (lane == 0) atomicAdd(&mx[trow + rlocal], p);
    }

    // Combine column partials across the 4 waves via LDS.
    lds_col[wave][lane * 4 + 0] = c0;
    lds_col[wave][lane * 4 + 1] = c1;
    lds_col[wave][lane * 4 + 2] = c2;
    lds_col[wave][lane * 4 + 3] = c3;

    // S1 partial per wave
    float s1w = waveReduceSum(s1_local);
    if (lane == 0) lds_s1[wave] = s1w;

    __syncthreads();

    // thread t owns tile-column t
    float csum = lds_col[0][tid] + lds_col[1][tid] + lds_col[2][tid] + lds_col[3][tid];
    atomicAdd(&my[tcol + tid], csum);

    if (tid == 0) {
        atomicAdd(s1, (lds_s1[0] + lds_s1[1]) + (lds_s1[2] + lds_s1[3]));
    }
}

// Epilogue 1: sum x*log2(x) over the 16384 marginals (mx ++ my contiguous in ws).
__global__ __launch_bounds__(256) void mi_marg(const float* __restrict__ marg,
                                               float* __restrict__ sxy) {
    const int tid  = threadIdx.x;
    const int lane = tid & 63;
    const int wave = tid >> 6;
    const int stride = gridDim.x * blockDim.x;

    float acc = 0.f;
    for (int i = blockIdx.x * blockDim.x + tid; i < NROWS + MCOLS; i += stride) {
        const float x = marg[i];
        if (x > 0.f) acc += x * __log2f(x);
    }

    acc = waveReduceSum(acc);
    __shared__ float lds[4];
    if (lane == 0) lds[wave] = acc;
    __syncthreads();
    if (tid == 0) atomicAdd(sxy, (lds[0] + lds[1]) + (lds[2] + lds[3]));
}

// Epilogue 2: combine.
__global__ void mi_final(const float* __restrict__ s1,
                         const float* __restrict__ sxy,
                         float* __restrict__ out) {
    out[0] = s1[0] - sxy[0];
}

extern "C" void kernel_launch(void* const* d_in, const int* in_sizes, int n_in,
                              void* d_out, int out_size, void* d_ws, size_t ws_size,
                              hipStream_t stream) {
    const float* C = (const float*)d_in[0];
    float* ws  = (float*)d_ws;
    float* mx  = ws;              // 8192
    float* my  = ws + NROWS;      // 8192 (contiguous after mx)
    float* s1  = ws + NROWS + MCOLS;      // 1
    float* sxy = ws + NROWS + MCOLS + 1;  // 1

    // zero accumulators (harness poisons ws with 0xAA; we must re-zero every call)
    hipMemsetAsync(d_ws, 0, (size_t)(NROWS + MCOLS + 2) * sizeof(float), stream);

    dim3 grid(MCOLS / 256, NROWS / 256);
    mi_main<<<grid, 256, 0, stream>>>(C, mx, my, s1);
    mi_marg<<<16, 256, 0, stream>>>(mx, sxy);
    mi_final<<<1, 1, 0, stream>>>(s1, sxy, (float*)d_out);
}

// Round 2
// 55.208 us; speedup vs baseline: 1.5607x; 1.5607x over previous
//
#include <hip/hip_runtime.h>

// Mutual information of an 8192x8192 fp32 contingency table.
// MI = sum_{C>0} C*log2(C) - sum_i mx_i*log2(mx_i) - sum_j my_j*log2(my_j)
// (exact rewrite: zero entries contribute nothing to the masked sums, so the
//  masked row/col sums equal the full marginals).
//
// Pass 1 (mi_main): 32x32 grid of 256-thread blocks, each owns a 256x256 tile.
//   - coalesced float4 row-segment loads (1 KB per wave per iteration)
//   - per-thread register column accumulators (thread always sees same 4 cols)
//   - row partials: ONE shfl_xor(32) + one ds_write into padded LDS per iter
//     (replaces a 6-deep butterfly per iteration), transposed reduce at end
//   - all partials written NON-atomically to unique ws slots -> no memset, no
//     atomics anywhere (ws is ~1 GB per harness poison; we use ~2.1 MB)
// Pass 2 (mi_ep1, 64 blocks): fold 32 partials per marginal, entropy terms,
//   plus distributed s1_arr sum -> 64 block partials.
// Pass 3 (mi_ep2, 1 wave): final 64-way sum -> out.

#define NROWS 8192
#define MCOLS 8192

__inline__ __device__ float waveReduceSum(float v) {
    #pragma unroll
    for (int off = 32; off > 0; off >>= 1)
        v += __shfl_xor(v, off, 64);
    return v;
}

__global__ __launch_bounds__(256) void mi_main(const float* __restrict__ C,
                                               float* __restrict__ P_rows,
                                               float* __restrict__ P_cols,
                                               float* __restrict__ s1_arr) {
    const int bx = blockIdx.x;            // column-block 0..31
    const int by = blockIdx.y;            // row-block 0..31
    const int tcol = bx * 256, trow = by * 256;
    const int tid  = threadIdx.x;
    const int lane = tid & 63;
    const int wave = tid >> 6;

    // lds_row[r][k]: bank = (r*33 + k) % 32 = (r + k) % 32 -> conflict-free
    __shared__ float lds_row[256][33];
    __shared__ float lds_col[4][256];
    __shared__ float lds_s1[4];

    float c0 = 0.f, c1 = 0.f, c2 = 0.f, c3 = 0.f;
    float s1_local = 0.f;

    const float* base = C + (size_t)trow * MCOLS + tcol + lane * 4;

    #pragma unroll 4
    for (int i = 0; i < 64; ++i) {
        const int r = i * 4 + wave;       // tile row handled by this wave
        const float4 v = *reinterpret_cast<const float4*>(base + (size_t)r * MCOLS);

        // masked C*log2(C)
        float t0 = (v.x > 0.f) ? v.x * __log2f(v.x) : 0.f;
        float t1 = (v.y > 0.f) ? v.y * __log2f(v.y) : 0.f;
        float t2 = (v.z > 0.f) ? v.z * __log2f(v.z) : 0.f;
        float t3 = (v.w > 0.f) ? v.w * __log2f(v.w) : 0.f;
        s1_local += (t0 + t1) + (t2 + t3);

        // register column accumulators
        c0 += v.x; c1 += v.y; c2 += v.z; c3 += v.w;

        // row partial: fold upper half onto lower, stage 32 partials in LDS
        float p = (v.x + v.y) + (v.z + v.w);
        p += __shfl_xor(p, 32, 64);
        if (lane < 32) lds_row[r][lane] = p;
    }

    // stage column partials
    lds_col[wave][lane * 4 + 0] = c0;
    lds_col[wave][lane * 4 + 1] = c1;
    lds_col[wave][lane * 4 + 2] = c2;
    lds_col[wave][lane * 4 + 3] = c3;

    // s1 partial per wave (one butterfly per kernel, not per iteration)
    const float s1w = waveReduceSum(s1_local);
    if (lane == 0) lds_s1[wave] = s1w;

    __syncthreads();

    // transposed row reduce: thread t owns tile-row t; 2-way bank alias = free
    float rs = 0.f;
    #pragma unroll
    for (int k = 0; k < 32; ++k) rs += lds_row[tid][k];
    P_rows[(size_t)bx * NROWS + trow + tid] = rs;

    // column reduce: thread t owns tile-col t
    const float cs = (lds_col[0][tid] + lds_col[1][tid]) +
                     (lds_col[2][tid] + lds_col[3][tid]);
    P_cols[(size_t)by * MCOLS + tcol + tid] = cs;

    if (tid == 0)
        s1_arr[by * 32 + bx] = (lds_s1[0] + lds_s1[1]) + (lds_s1[2] + lds_s1[3]);
}

// 64 blocks: b<32 -> rows, b>=32 -> cols. Each block also folds 16 s1 entries.
__global__ __launch_bounds__(256) void mi_ep1(const float* __restrict__ P_rows,
                                              const float* __restrict__ P_cols,
                                              const float* __restrict__ s1_arr,
                                              float* __restrict__ partials) {
    const int b    = blockIdx.x;
    const int tid  = threadIdx.x;
    const int lane = tid & 63;
    const int wave = tid >> 6;

    const float* P = (b < 32) ? P_rows : P_cols;
    const int idx  = ((b & 31) << 8) + tid;      // marginal index 0..8191

    float x = 0.f;
    #pragma unroll
    for (int k = 0; k < 32; ++k) x += P[(size_t)k * 8192 + idx];

    float acc = (x > 0.f) ? -x * __log2f(x) : 0.f;   // entropy enters negated
    if (tid < 16) acc += s1_arr[b * 16 + tid];       // distributed s1 sum

    acc = waveReduceSum(acc);
    __shared__ float lds[4];
    if (lane == 0) lds[wave] = acc;
    __syncthreads();
    if (tid == 0) partials[b] = (lds[0] + lds[1]) + (lds[2] + lds[3]);
}

__global__ void mi_ep2(const float* __restrict__ partials,
                       float* __restrict__ out) {
    float v = partials[threadIdx.x];  // exactly 64 threads
    v = waveReduceSum(v);
    if (threadIdx.x == 0) out[0] = v;
}

extern "C" void kernel_launch(void* const* d_in, const int* in_sizes, int n_in,
                              void* d_out, int out_size, void* d_ws, size_t ws_size,
                              hipStream_t stream) {
    const float* C = (const float*)d_in[0];
    float* ws      = (float*)d_ws;
    float* P_rows  = ws;                    // 32*8192
    float* P_cols  = ws + 262144;           // 32*8192
    float* s1_arr  = ws + 524288;           // 1024
    float* parts   = ws + 525312;           // 64
    // total ws use: ~2.06 MB (ws is ~1 GB per harness poison fill)

    dim3 grid(MCOLS / 256, NROWS / 256);
    mi_main<<<grid, 256, 0, stream>>>(C, P_rows, P_cols, s1_arr);
    mi_ep1<<<64, 256, 0, stream>>>(P_rows, P_cols, s1_arr, parts);
    mi_ep2<<<1, 64, 0, stream>>>(parts, (float*)d_out);
}